// Round 3
// baseline (957.569 us; speedup 1.0000x reference)
//
#include <hip/hip_runtime.h>
#include <math.h>

// Problem constants (fixed by setup_inputs)
#define NCH 128
#define IMW 640
#define IMH 480
#define HW (IMW * IMH)
#define THREADS 512
#define WPB (THREADS / 64)   // waves per block
#define GBLK 512             // fused partial blocks
#define TSTRIDE (3 * NCH)    // interleaved (pix, map, ch) stride = 384 floats

// state layout in d_ws (doubles)
#define S_R    0   // 9: current (accepted) R, row-major
#define S_T    9   // 3: current t
#define S_RC   12  // 9: candidate R
#define S_TC   21  // 3: candidate t
#define S_LAM  24
#define S_LR   25
#define S_PREV 26
#define S_G    32  // 27: stashed reduced Grad(6) + Hess upper-tri(21) at accepted pose
#define S_TOTAL 64

#define PCOLS 29   // per-block partials: 27 grad/hess + cost-sum + count

__device__ __forceinline__ float sel6(int k, float v0, float v1, float v2,
                                      float v3, float v4, float v5) {
  float r = v0;
  r = (k == 1) ? v1 : r;
  r = (k == 2) ? v2 : r;
  r = (k == 3) ? v3 : r;
  r = (k == 4) ? v4 : r;
  r = (k == 5) ? v5 : r;
  return r;
}

struct ProjR {
  float x, y, z;
  int pix;
  bool m;
};

__device__ __forceinline__ ProjR project_pt(const float* __restrict__ pts, int n,
                                            const float R[9], const float T[3],
                                            const float Kv[9]) {
  float px = pts[3 * n + 0], py = pts[3 * n + 1], pz = pts[3 * n + 2];
  ProjR o;
  o.x = R[0] * px + R[1] * py + R[2] * pz + T[0];
  o.y = R[3] * px + R[4] * py + R[5] * pz + T[1];
  o.z = R[6] * px + R[7] * py + R[8] * pz + T[2];
  float pr0 = Kv[0] * o.x + Kv[1] * o.y + Kv[2] * o.z;
  float pr1 = Kv[3] * o.x + Kv[4] * o.y + Kv[5] * o.z;
  float pr2 = Kv[6] * o.x + Kv[7] * o.y + Kv[8] * o.z;
  float u = fminf(fmaxf(pr0 / pr2, -1000000.0f), 1000000.0f);
  float v = fminf(fmaxf(pr1 / pr2, -1000000.0f), 1000000.0f);
  int p2x = (int)rintf(u) - 1;   // round-half-even matches jnp.round
  int p2y = (int)rintf(v) - 1;
  o.m = (p2x >= 0) && (p2y >= 0) && (p2x < IMW) && (p2y < IMH);
  int r = min(max(p2y, 0), IMH - 1);
  int c = min(max(p2x, 0), IMW - 1);
  o.pix = r * IMW + c;
  return o;
}

// Per-point 2x6 Jacobian rows A0, A1
__device__ __forceinline__ void jac_rows(const ProjR& p, float fx, float fy,
                                         float A0[6], float A1[6]) {
  float Zs = (fabsf(p.z) > 1e-6f) ? p.z : 1e-6f;
  float iz = 1.0f / Zs;
  float j00 = fx * iz;
  float j02 = -fx * p.x * iz * iz;
  float j11 = fy * iz;
  float j12 = -fy * p.y * iz * iz;
  A0[0] = j00; A0[1] = 0.0f; A0[2] = j02;
  A0[3] = j02 * p.y; A0[4] = j00 * p.z - j02 * p.x; A0[5] = -j00 * p.y;
  A1[0] = 0.0f; A1[1] = j11; A1[2] = j12;
  A1[3] = -j11 * p.z + j12 * p.y; A1[4] = -j12 * p.x; A1[5] = j11 * p.x;
}

__global__ void init_kernel(const float* __restrict__ Rin,
                            const float* __restrict__ tin,
                            double* __restrict__ st) {
  int i = threadIdx.x;
  if (i < 9) { st[S_R + i] = (double)Rin[i]; st[S_RC + i] = (double)Rin[i]; }
  if (i < 3) { st[S_T + i] = (double)tin[i]; st[S_TC + i] = (double)tin[i]; }
  if (i == 0) { st[S_LAM] = 0.01; st[S_LR] = 1.0; st[S_PREV] = 0.0; }
}

// ---- (C,H,W) -> interleaved (pix, map, ch) transpose, all 3 maps ----
// Output layout: t[pix*384 + map*128 + c]. Each point's gather in the fused
// kernel then reads ONE contiguous 1536B region instead of 3 distant 512B
// regions (one page / 24 fully-used cache lines per point).
__global__ __launch_bounds__(256) void transpose3_kernel(
    const float* __restrict__ f, const float* __restrict__ gx,
    const float* __restrict__ gy, float* __restrict__ t) {
  __shared__ float tile[64][NCH + 1];  // +1 pad: break 128-stride bank alias
  const int map = blockIdx.y;
  const float* in = (map == 0) ? f : (map == 1) ? gx : gy;
  const int pix0 = blockIdx.x * 64;
  // load: float4 along pixels, coalesced
  for (int k = threadIdx.x; k < 64 * NCH / 4; k += 256) {
    int c = k >> 4;            // 16 float4 per channel row
    int p4 = (k & 15) * 4;
    float4 v = ((const float4*)(in + (size_t)c * HW + pix0))[k & 15];
    tile[p4 + 0][c] = v.x;
    tile[p4 + 1][c] = v.y;
    tile[p4 + 2][c] = v.z;
    tile[p4 + 3][c] = v.w;
  }
  __syncthreads();
  // store: float4 along channels, 512B per (pixel,map)
  for (int k = threadIdx.x; k < 64 * NCH / 4; k += 256) {
    int px = k >> 5;           // 32 float4 per pixel
    int c4 = (k & 31) * 4;
    float4 v = make_float4(tile[px][c4], tile[px][c4 + 1], tile[px][c4 + 2],
                           tile[px][c4 + 3]);
    ((float4*)(t + (size_t)(pix0 + px) * TSTRIDE + (size_t)map * NCH))[k & 31] = v;
  }
}

// ---- fused cost+grad at CANDIDATE pose ----
// LM identity: grad/Hess at a pose is a pure function of the pose. The cost
// kernel's projection/gather at the candidate == next iteration's grad
// projection/gather when accepted; on reject the previous stash is reused.
// So one fused pass per iteration replaces grad+cost passes entirely.
// Partials layout per block: [0..26] grad(6)+hess(21), [27] sum(err^2), [28] count.
template <bool TRANS>
__global__ __launch_bounds__(THREADS) void fused_kernel(
    const float* __restrict__ pts, const float* __restrict__ fref,
    const float* __restrict__ mf, const float* __restrict__ mgx,
    const float* __restrict__ mgy, const float* __restrict__ Kmat,
    const double* __restrict__ st, double* __restrict__ part, int N) {
  const int lane = threadIdx.x & 63;
  const int wib = threadIdx.x >> 6;
  const int gw = blockIdx.x * WPB + wib;
  const int nw = gridDim.x * WPB;

  float R[9], T[3], Kv[9];
#pragma unroll
  for (int i = 0; i < 9; ++i) { R[i] = (float)st[S_RC + i]; Kv[i] = Kmat[i]; }
#pragma unroll
  for (int i = 0; i < 3; ++i) T[i] = (float)st[S_TC + i];
  const float fx = Kv[0], fy = Kv[4];

  int kq = 0, lq = 0;
  if (lane < 6) {
    kq = lane; lq = lane;
  } else if (lane < 27) {
    int q = lane - 6, k = 0;
    while (q >= 6 - k) { q -= 6 - k; ++k; }
    kq = k; lq = k + q;
  }

  double acc = 0.0, csum = 0.0, cnt = 0.0;

  for (int n = gw; n < N; n += nw) {
    ProjR p = project_pt(pts, n, R, T, Kv);
    if (!p.m) continue;  // wave-uniform (all lanes share point n)
    float A0[6], A1[6];
    jac_rows(p, fx, fy, A0, A1);

    float e0, e1, gx0, gx1, gy0, gy1;
    if (TRANS) {
      // mf points at the interleaved (pix, map, ch) buffer
      const size_t base = (size_t)p.pix * TSTRIDE + 2 * lane;
      float2 f  = *(const float2*)(mf + base);
      float2 gx = *(const float2*)(mf + base + NCH);
      float2 gy = *(const float2*)(mf + base + 2 * NCH);
      float2 fr = *(const float2*)(fref + (size_t)n * NCH + 2 * lane);
      e0 = f.x - fr.x; e1 = f.y - fr.y;
      gx0 = gx.x; gx1 = gx.y; gy0 = gy.x; gy1 = gy.y;
    } else {
      const size_t base = (size_t)p.pix;
      const int c0 = lane, c1 = lane + 64;
      float f0 = mf[(size_t)c0 * HW + base], f1 = mf[(size_t)c1 * HW + base];
      gx0 = mgx[(size_t)c0 * HW + base]; gx1 = mgx[(size_t)c1 * HW + base];
      gy0 = mgy[(size_t)c0 * HW + base]; gy1 = mgy[(size_t)c1 * HW + base];
      float r0 = fref[(size_t)n * NCH + c0], r1 = fref[(size_t)n * NCH + c1];
      e0 = f0 - r0; e1 = f1 - r1;
    }

    // cost accumulation (register-resident; free vs a separate cost pass)
    csum += (double)(e0 * e0 + e1 * e1);
    if (lane == 0) cnt += 1.0;

    float sxx = gx0 * gx0 + gx1 * gx1;
    float sxy = gx0 * gy0 + gx1 * gy1;
    float syy = gy0 * gy0 + gy1 * gy1;
    float sxe = gx0 * e0 + gx1 * e1;
    float sye = gy0 * e0 + gy1 * e1;
#pragma unroll
    for (int off = 32; off > 0; off >>= 1) {
      sxx += __shfl_xor(sxx, off);
      sxy += __shfl_xor(sxy, off);
      syy += __shfl_xor(syy, off);
      sxe += __shfl_xor(sxe, off);
      sye += __shfl_xor(sye, off);
    }
    float a0k = sel6(kq, A0[0], A0[1], A0[2], A0[3], A0[4], A0[5]);
    float a1k = sel6(kq, A1[0], A1[1], A1[2], A1[3], A1[4], A1[5]);
    float a0l = sel6(lq, A0[0], A0[1], A0[2], A0[3], A0[4], A0[5]);
    float a1l = sel6(lq, A1[0], A1[1], A1[2], A1[3], A1[4], A1[5]);
    float contrib;
    if (lane < 6)
      contrib = sxe * a0k + sye * a1k;
    else
      contrib = sxx * a0k * a0l + sxy * (a0k * a1l + a1k * a0l) +
                syy * a1k * a1l;
    if (lane < 27) acc += (double)contrib;
  }

  // wave-level cost reduce (once per kernel, not per point)
#pragma unroll
  for (int off = 32; off > 0; off >>= 1) {
    csum += __shfl_xor(csum, off);
    cnt += __shfl_xor(cnt, off);
  }

  __shared__ double red[WPB][PCOLS];
  if (lane < 27) red[wib][lane] = acc;
  if (lane == 0) { red[wib][27] = csum; red[wib][28] = cnt; }
  __syncthreads();
  if (wib == 0 && lane < PCOLS) {
    double s = 0.0;
#pragma unroll
    for (int w = 0; w < WPB; ++w) s += red[w][lane];
    part[(size_t)blockIdx.x * PCOLS + lane] = s;
  }
}

// Reduce partials; accept/reject; stash grads on accept; LM solve next
// candidate with UPDATED lambda/lr; write output pose. Merges the old
// solve_kernel + update_kernel into one dispatch.
__global__ void update_solve_kernel(const double* __restrict__ part, int GB,
                                    double* __restrict__ st,
                                    float* __restrict__ out, int is_init) {
  __shared__ double red[16][PCOLS];
  __shared__ double tot[PCOLS];
  int q = threadIdx.x & 31;
  int chunk = threadIdx.x >> 5;  // 0..15
  if (q < PCOLS) {
    double s = 0.0;
    for (int b = chunk; b < GB; b += 16) s += part[(size_t)b * PCOLS + q];
    red[chunk][q] = s;
  }
  __syncthreads();
  if (threadIdx.x < PCOLS) {
    double t = 0.0;
#pragma unroll
    for (int ch = 0; ch < 16; ++ch) t += red[ch][threadIdx.x];
    tot[threadIdx.x] = t;
  }
  __syncthreads();
  if (threadIdx.x == 0) {
    double nc = 0.5 * tot[27] / fmax(tot[28], 1.0);
    bool accept;
    if (is_init) {
      accept = true;
      st[S_PREV] = nc;
      // lam/lr keep init values (0.01 / 1.0)
    } else {
      accept = (nc <= st[S_PREV]);
      double lam = st[S_LAM] * (accept ? 0.1 : 10.0);
      st[S_LAM] = fmin(fmax(lam, 1e-6), 1e4);
      st[S_LR] = accept ? 1.0 : fmin(fmax(0.1 * st[S_LR], 1e-3), 1.0);
      if (accept) st[S_PREV] = nc;
    }
    if (accept) {
      for (int i = 0; i < 9; ++i) st[S_R + i] = st[S_RC + i];
      for (int i = 0; i < 3; ++i) st[S_T + i] = st[S_TC + i];
      for (int j = 0; j < 27; ++j) st[S_G + j] = tot[j];
      // on reject: stash already holds grad/Hess at the accepted pose
    }
    // output current accepted pose (final dispatch writes the answer)
    for (int i = 0; i < 9; ++i) out[i] = (float)st[S_R + i];
    for (int i = 0; i < 3; ++i) out[9 + i] = (float)st[S_T + i];

    // ---- LM solve for the NEXT candidate, using updated lam/lr ----
    double Grad[6], Hs[6][6];
    for (int j = 0; j < 6; ++j) Grad[j] = st[S_G + j];
    int qq = 0;
    for (int k = 0; k < 6; ++k)
      for (int l = k; l < 6; ++l) { Hs[k][l] = Hs[l][k] = st[S_G + 6 + qq]; ++qq; }
    double lam = st[S_LAM], lr = st[S_LR];
    double M[6][7];
    for (int i = 0; i < 6; ++i) {
      for (int j = 0; j < 6; ++j) M[i][j] = Hs[i][j];
      M[i][i] += lam * (Hs[i][i] + 1e-9);
      M[i][6] = Grad[i];
    }
    for (int c = 0; c < 6; ++c) {
      int piv = c;
      double mx = fabs(M[c][c]);
      for (int r = c + 1; r < 6; ++r) {
        double a = fabs(M[r][c]);
        if (a > mx) { mx = a; piv = r; }
      }
      if (piv != c)
        for (int j = 0; j < 7; ++j) {
          double tmp = M[c][j]; M[c][j] = M[piv][j]; M[piv][j] = tmp;
        }
      double pv = M[c][c];
      if (pv == 0.0) pv = 1e-30;
      for (int r = c + 1; r < 6; ++r) {
        double f = M[r][c] / pv;
        for (int j = c; j < 7; ++j) M[r][j] -= f * M[c][j];
      }
    }
    double xs[6];
    for (int i = 5; i >= 0; --i) {
      double v = M[i][6];
      for (int j = i + 1; j < 6; ++j) v -= M[i][j] * xs[j];
      double pv = M[i][i];
      if (pv == 0.0) pv = 1e-30;
      xs[i] = v / pv;
    }
    double dt[3] = {-lr * xs[0], -lr * xs[1], -lr * xs[2]};
    double dw[3] = {-lr * xs[3], -lr * xs[4], -lr * xs[5]};
    double th2 = dw[0] * dw[0] + dw[1] * dw[1] + dw[2] * dw[2];
    double th = sqrt(th2 + 1e-24);
    double a, b;
    if (th < 1e-4) { a = 1.0 - th2 / 6.0; b = 0.5 - th2 / 24.0; }
    else { a = sin(th) / th; b = (1.0 - cos(th)) / (th2 + 1e-24); }
    double W[3][3] = {{0, -dw[2], dw[1]}, {dw[2], 0, -dw[0]}, {-dw[1], dw[0], 0}};
    double W2[3][3];
    for (int i = 0; i < 3; ++i)
      for (int j = 0; j < 3; ++j) {
        double s = 0.0;
        for (int k = 0; k < 3; ++k) s += W[i][k] * W[k][j];
        W2[i][j] = s;
      }
    double dr[3][3];
    for (int i = 0; i < 3; ++i)
      for (int j = 0; j < 3; ++j)
        dr[i][j] = ((i == j) ? 1.0 : 0.0) + a * W[i][j] + b * W2[i][j];
    for (int i = 0; i < 3; ++i) {
      for (int j = 0; j < 3; ++j) {
        double s = 0.0;
        for (int k = 0; k < 3; ++k) s += dr[i][k] * st[S_R + k * 3 + j];
        st[S_RC + i * 3 + j] = s;
      }
      double s = 0.0;
      for (int k = 0; k < 3; ++k) s += dr[i][k] * st[S_T + k];
      st[S_TC + i] = s + dt[i];
    }
  }
}

extern "C" void kernel_launch(void* const* d_in, const int* in_sizes, int n_in,
                              void* d_out, int out_size, void* d_ws, size_t ws_size,
                              hipStream_t stream) {
  const float* pts  = (const float*)d_in[0];
  const float* fref = (const float*)d_in[1];
  const float* fm   = (const float*)d_in[2];
  const float* gxm  = (const float*)d_in[3];
  const float* gym  = (const float*)d_in[4];
  const float* Kmat = (const float*)d_in[5];
  const float* Rin  = (const float*)d_in[6];
  const float* tin  = (const float*)d_in[7];
  const int N = in_sizes[0] / 3;

  double* st = (double*)d_ws;
  double* part = st + S_TOTAL;
  float* out = (float*)d_out;

  const size_t state_doubles = S_TOTAL + (size_t)GBLK * PCOLS;
  const size_t map_floats = (size_t)HW * NCH;               // 39.32 M
  const size_t need_fast =
      state_doubles * sizeof(double) + 3 * map_floats * sizeof(float) + 256;

  init_kernel<<<1, 64, 0, stream>>>(Rin, tin, st);

  if (ws_size >= need_fast) {
    // fast path: transpose maps into one interleaved (pix, map, ch) buffer
    float* tmap = (float*)(st + state_doubles);
    transpose3_kernel<<<dim3(HW / 64, 3), 256, 0, stream>>>(fm, gxm, gym, tmap);
    // fused at init pose (S_RC == init): yields prev_cost AND grad at P1
    fused_kernel<true><<<GBLK, THREADS, 0, stream>>>(pts, fref, tmap, tmap, tmap,
                                                     Kmat, st, part, N);
    update_solve_kernel<<<1, 512, 0, stream>>>(part, GBLK, st, out, 1);
    for (int it = 0; it < 10; ++it) {
      fused_kernel<true><<<GBLK, THREADS, 0, stream>>>(pts, fref, tmap, tmap,
                                                       tmap, Kmat, st, part, N);
      update_solve_kernel<<<1, 512, 0, stream>>>(part, GBLK, st, out, 0);
    }
  } else {
    // fallback: gather directly from (C,H,W)
    fused_kernel<false><<<GBLK, THREADS, 0, stream>>>(pts, fref, fm, gxm, gym,
                                                      Kmat, st, part, N);
    update_solve_kernel<<<1, 512, 0, stream>>>(part, GBLK, st, out, 1);
    for (int it = 0; it < 10; ++it) {
      fused_kernel<false><<<GBLK, THREADS, 0, stream>>>(pts, fref, fm, gxm, gym,
                                                        Kmat, st, part, N);
      update_solve_kernel<<<1, 512, 0, stream>>>(part, GBLK, st, out, 0);
    }
  }
}